// Round 16
// baseline (190.173 us; speedup 1.0000x reference)
//
#include <hip/hip_runtime.h>

#define T_SEQ 512
#define EMB 32
#define HID 128
#define BB 2          // batch rows per block -> 256 blocks, 1 block/CU
#define LDSW 160      // h row stride in bf16 elems

typedef __attribute__((ext_vector_type(8))) short short8;   // 8 bf16
typedef __attribute__((ext_vector_type(4))) float f32x4;

__device__ __forceinline__ short f2bf(float f) {
  union { float f; unsigned u; } v; v.f = f;
  unsigned r = (v.u + 0x7FFFu + ((v.u >> 16) & 1u)) >> 16;  // RNE
  return (short)r;
}

__device__ __forceinline__ short f2bfu(unsigned u) {      // f32 bits -> bf16 RNE
  unsigned r = (u + 0x7FFFu + ((u >> 16) & 1u)) >> 16;
  return (short)r;
}

__device__ __forceinline__ float tanh_fast(float a) {
  float e = __expf(2.0f * a);
  return 1.0f - 2.0f * __builtin_amdgcn_rcpf(e + 1.0f);
}

#define MFMA(a, b, c) __builtin_amdgcn_mfma_f32_16x16x32_bf16((a), (b), (c), 0, 0, 0)

// Single fused kernel, R6 chain + x-work software-pipelined off the chain:
//  - step t computes p(t+1) = x(t+1)@Wx + bias in the h-MFMA dep shadow;
//  - p(t) enters step t as the C operand of the first a-chain MFMA
//    (R2-verified summation order), so the chain tail has NO xw add;
//  - x loaded via 8 scalar asm global_load_dword/lane (R6-proven shape),
//    4-slot ring, consume-slot != fill-slot (no reg copy needed);
//  - exact counted vmcnt: preloop 24, peel 16/17/18, steady 19;
//    hoist fence = s_waitcnt asm + sched_barrier(0)  (rule #18).
__global__ __launch_bounds__(256) void rnn_fused_kernel(
    const float* __restrict__ x, const float* __restrict__ Wx,
    const float* __restrict__ Wh, const float* __restrict__ bh,
    float* __restrict__ out) {
  __shared__ short hbuf[2][BB][LDSW];

  const int tid = threadIdx.x;
  const int wid = tid >> 6;        // wave 0..3, owns cols [32w, 32w+32)
  const int lane = tid & 63;
  const int l4 = lane >> 4, lm = lane & 15;
  const int row0 = blockIdx.x * BB;
  const int colbase = wid * 32;

  for (int i = tid; i < 2 * BB * LDSW; i += 256) ((short*)hbuf)[i] = 0;

  // ---- weights into registers (B-frag: col = lane&15, k = 8*(lane>>4)+j) ----
  short8 whf[2][4]; short8 wxf[2]; float bv[2];
#pragma unroll
  for (int nt = 0; nt < 2; ++nt) {
    const int col = colbase + 16 * nt + lm;
    bv[nt] = bh[col];
#pragma unroll
    for (int kb = 0; kb < 4; ++kb) {
      short8 f;
#pragma unroll
      for (int j = 0; j < 8; ++j)
        f[j] = f2bf(Wh[(size_t)(32 * kb + 8 * l4 + j) * HID + col]);
      whf[nt][kb] = f;
    }
    short8 fx;
#pragma unroll
    for (int j = 0; j < 8; ++j)
      fx[j] = f2bf(Wx[(size_t)(8 * l4 + j) * HID + col]);
    wxf[nt] = fx;
  }

  const int rsel = l4 & 1;         // batch row parity this lane outputs
  const int csel = l4 >> 1;        // which 16-col tile
  const int ocol = colbase + 16 * csel + lm;

  // byte offsets (u32-safe: x 33.5MB, out 134MB)
  const unsigned x_off0 =
      ((unsigned)(row0 + (lm & 1)) * (T_SEQ * EMB) + (unsigned)(8 * l4)) * 4u;
  const unsigned out_off0 =
      ((unsigned)(row0 + rsel) * T_SEQ) * (HID * 4) + (unsigned)ocol * 4;
  const float* xb = x;
  float* outb = out;
  float* hfinp = out + (size_t)512 * T_SEQ * HID + (size_t)(row0 + rsel) * HID + ocol;

  // LDS ptrs: A-frag read row = lm&1 (k-offset 8*l4 folded); write own (rsel,ocol)
  const short* hr0 = &hbuf[0][lm & 1][8 * l4];
  const short* hr1 = &hbuf[1][lm & 1][8 * l4];
  short* hw0 = &hbuf[0][rsel][ocol];
  short* hw1 = &hbuf[1][rsel][ocol];

  const f32x4 z_  = {0.f, 0.f, 0.f, 0.f};
  const f32x4 cb0 = {bv[0], bv[0], bv[0], bv[0]};   // bias as x-MFMA C
  const f32x4 cb1 = {bv[1], bv[1], bv[1], bv[1]};

  float th_last = 0.f;

  __syncthreads();  // zero-init visible; drains ALL prior vmem -> clean vmcnt baseline

  // ---- x ring: 4 slots x 8 scalar dwords; slot s holds x(t) with t%4==s ----
  unsigned q00,q01,q02,q03,q04,q05,q06,q07;
  unsigned q10,q11,q12,q13,q14,q15,q16,q17;
  unsigned q20,q21,q22,q23,q24,q25,q26,q27;
  unsigned q30,q31,q32,q33,q34,q35,q36,q37;

#define XL(D, OFF) \
  asm volatile("global_load_dword %0, %1, %2" : "=v"(D) : "v"(OFF), "s"(xb))
#define XL8(A0,A1,A2,A3,A4,A5,A6,A7, TT) do {                                    \
    const unsigned b_ = x_off0 + (unsigned)(TT) * 128u;                          \
    XL(A0, b_);       XL(A1, b_ + 4u);  XL(A2, b_ + 8u);  XL(A3, b_ + 12u);      \
    XL(A4, b_ + 16u); XL(A5, b_ + 20u); XL(A6, b_ + 24u); XL(A7, b_ + 28u);      \
  } while (0)

  XL8(q00,q01,q02,q03,q04,q05,q06,q07, 0);
  XL8(q10,q11,q12,q13,q14,q15,q16,q17, 1);
  XL8(q20,q21,q22,q23,q24,q25,q26,q27, 2);
  XL8(q30,q31,q32,q33,q34,q35,q36,q37, 3);

  f32x4 pA0, pA1, pB0, pB1;
  // pre-loop: p(0) from slot0 (wait: slots1-3 outstanding = 24)
  asm volatile("s_waitcnt vmcnt(24)" ::: "memory");
  __builtin_amdgcn_sched_barrier(0);
  {
    short8 xa_;
    xa_[0]=f2bfu(q00); xa_[1]=f2bfu(q01); xa_[2]=f2bfu(q02); xa_[3]=f2bfu(q03);
    xa_[4]=f2bfu(q04); xa_[5]=f2bfu(q05); xa_[6]=f2bfu(q06); xa_[7]=f2bfu(q07);
    pA0 = MFMA(xa_, wxf[0], cb0);
    pA1 = MFMA(xa_, wxf[1], cb1);
  }

  // Per step t: [4 ds_read] [8 h-MFMA, a-chain C = p(t)] [wait vmcnt(WN) +
  // sched_barrier] [f2bf slot(t+1)] [refill slot(t%4) <- x(t+4), clamped]
  // [p(t+1) 2 MFMAs] [tail: sel+add, tanh] [ds_write] [asm store] [lgkm+barrier]
#define RSTEP(T, WN, PAR, C0,C1,C2,C3,C4,C5,C6,C7, F0,F1,F2,F3,F4,F5,F6,F7,     \
              PIN0, PIN1, POUT0, POUT1) do {                                     \
    const short* hb_ = (PAR) ? hr0 : hr1;   /* prev = PAR^1 */                   \
    short8 ah0 = *(const short8*)(hb_ + 0);                                      \
    short8 ah1 = *(const short8*)(hb_ + 32);                                     \
    short8 ah2 = *(const short8*)(hb_ + 64);                                     \
    short8 ah3 = *(const short8*)(hb_ + 96);                                     \
    f32x4 a0 = MFMA(ah0, whf[0][0], PIN0);   /* p(t) enters as C */              \
    f32x4 a1 = MFMA(ah0, whf[1][0], PIN1);                                       \
    f32x4 b0 = MFMA(ah2, whf[0][2], z_);                                         \
    f32x4 b1 = MFMA(ah2, whf[1][2], z_);                                         \
    a0 = MFMA(ah1, whf[0][1], a0);                                               \
    a1 = MFMA(ah1, whf[1][1], a1);                                               \
    b0 = MFMA(ah3, whf[0][3], b0);                                               \
    b1 = MFMA(ah3, whf[1][3], b1);                                               \
    asm volatile("s_waitcnt vmcnt(" #WN ")" ::: "memory");                       \
    __builtin_amdgcn_sched_barrier(0);                                           \
    short8 xa_;                                                                  \
    xa_[0]=f2bfu(C0); xa_[1]=f2bfu(C1); xa_[2]=f2bfu(C2); xa_[3]=f2bfu(C3);      \
    xa_[4]=f2bfu(C4); xa_[5]=f2bfu(C5); xa_[6]=f2bfu(C6); xa_[7]=f2bfu(C7);      \
    { int tl_ = (T) + 4; if (tl_ > T_SEQ - 1) tl_ = T_SEQ - 1;                   \
      XL8(F0,F1,F2,F3,F4,F5,F6,F7, tl_); }                                       \
    POUT0 = MFMA(xa_, wxf[0], cb0);          /* p(t+1), off-chain */             \
    POUT1 = MFMA(xa_, wxf[1], cb1);                                              \
    float vA0 = rsel ? a0[1] : a0[0];                                            \
    float vB0 = rsel ? b0[1] : b0[0];                                            \
    float vA1 = rsel ? a1[1] : a1[0];                                            \
    float vB1 = rsel ? b1[1] : b1[0];                                            \
    float v_ = csel ? (vA1 + vB1) : (vA0 + vB0);                                 \
    float th_ = tanh_fast(v_);                                                   \
    *((PAR) ? hw1 : hw0) = f2bf(th_);   /* cur = PAR; 1 ds_write_b16 */          \
    asm volatile("global_store_dword %0, %1, %2"                                 \
                 :: "v"(out_off0 + (unsigned)(T) * 512u), "v"(th_), "s"(outb));  \
    th_last = th_;                                                               \
    asm volatile("s_waitcnt lgkmcnt(0)\n\ts_barrier" ::: "memory");              \
  } while (0)

  // peel (exact counts while the 9-ops/step pattern fills)
  RSTEP(0, 16, 0, q10,q11,q12,q13,q14,q15,q16,q17,
                  q00,q01,q02,q03,q04,q05,q06,q07, pA0,pA1, pB0,pB1);
  RSTEP(1, 17, 1, q20,q21,q22,q23,q24,q25,q26,q27,
                  q10,q11,q12,q13,q14,q15,q16,q17, pB0,pB1, pA0,pA1);
  RSTEP(2, 18, 0, q30,q31,q32,q33,q34,q35,q36,q37,
                  q20,q21,q22,q23,q24,q25,q26,q27, pA0,pA1, pB0,pB1);
  RSTEP(3, 19, 1, q00,q01,q02,q03,q04,q05,q06,q07,
                  q30,q31,q32,q33,q34,q35,q36,q37, pB0,pB1, pA0,pA1);
  for (int tb = 4; tb < T_SEQ; tb += 4) {
    RSTEP(tb + 0, 19, 0, q10,q11,q12,q13,q14,q15,q16,q17,
                         q00,q01,q02,q03,q04,q05,q06,q07, pA0,pA1, pB0,pB1);
    RSTEP(tb + 1, 19, 1, q20,q21,q22,q23,q24,q25,q26,q27,
                         q10,q11,q12,q13,q14,q15,q16,q17, pB0,pB1, pA0,pA1);
    RSTEP(tb + 2, 19, 0, q30,q31,q32,q33,q34,q35,q36,q37,
                         q20,q21,q22,q23,q24,q25,q26,q27, pA0,pA1, pB0,pB1);
    RSTEP(tb + 3, 19, 1, q00,q01,q02,q03,q04,q05,q06,q07,
                         q30,q31,q32,q33,q34,q35,q36,q37, pB0,pB1, pA0,pA1);
  }
#undef RSTEP
#undef XL8
#undef XL

  *hfinp = th_last;  // final h (t = T-1), off the loop
}

extern "C" void kernel_launch(void* const* d_in, const int* in_sizes, int n_in,
                              void* d_out, int out_size, void* d_ws, size_t ws_size,
                              hipStream_t stream) {
  const float* x  = (const float*)d_in[0];
  const float* Wx = (const float*)d_in[1];
  const float* Wh = (const float*)d_in[2];
  const float* bh = (const float*)d_in[3];
  float* out = (float*)d_out;
  (void)in_sizes; (void)n_in; (void)out_size; (void)d_ws; (void)ws_size;
  rnn_fused_kernel<<<512 / BB, 256, 0, stream>>>(x, Wx, Wh, bh, out);
}

// Round 17
// 116.925 us; speedup vs baseline: 1.6265x; 1.6265x over previous
//
#include <hip/hip_runtime.h>

#define T_SEQ 512
#define EMB 32
#define HID 128
#define BB 2          // batch rows per block -> 256 blocks, 1 block/CU
#define LDSW 160      // h row stride in bf16 elems
#define TCH 128       // x timesteps per LDS chunk (4 chunks total)

typedef __attribute__((ext_vector_type(8))) short short8;   // 8 bf16
typedef __attribute__((ext_vector_type(4))) short short4v;  // 4 bf16
typedef __attribute__((ext_vector_type(4))) float f32x4;

__device__ __forceinline__ short f2bf(float f) {
  union { float f; unsigned u; } v; v.f = f;
  unsigned r = (v.u + 0x7FFFu + ((v.u >> 16) & 1u)) >> 16;  // RNE
  return (short)r;
}

__device__ __forceinline__ float tanh_fast(float a) {
  float e = __expf(2.0f * a);
  return 1.0f - 2.0f * __builtin_amdgcn_rcpf(e + 1.0f);
}

#define MFMA(a, b, c) __builtin_amdgcn_mfma_f32_16x16x32_bf16((a), (b), (c), 0, 0, 0)

// R15 structure (LDS-staged x, zero in-loop vmem loads) + p-pipelining:
// step t computes p(t+1)=x(t+1)@Wx+bias in the h-MFMA dep shadow (its 2 MFMAs
// have no consumer until after the next barrier); p(t) enters step t as the C
// operand of the first a-chain MFMA (R2/R6-verified ordering). The serial
// chain is: barrier -> 4 ds_read -> depth-2 MFMA -> 2-way tail -> tanh ->
// ds_write. Chunk boundary: last step skips p-next; standalone PCOMP after
// the staging sync. (R16's global-load ring regressed 40% - reverted.)
__global__ __launch_bounds__(256) void rnn_fused_kernel(
    const float* __restrict__ x, const float* __restrict__ Wx,
    const float* __restrict__ Wh, const float* __restrict__ bh,
    float* __restrict__ out) {
  __shared__ short hbuf[2][BB][LDSW];          // 1280 B
  __shared__ short xlds[TCH][BB][EMB];         // 16 KB: [t&127][row][e]

  const int tid = threadIdx.x;
  const int wid = tid >> 6;        // wave 0..3, owns cols [32w, 32w+32)
  const int lane = tid & 63;
  const int l4 = lane >> 4, lm = lane & 15;
  const int row0 = blockIdx.x * BB;
  const int colbase = wid * 32;

  for (int i = tid; i < 2 * BB * LDSW; i += 256) ((short*)hbuf)[i] = 0;

  // ---- weights into registers (B-frag: col = lane&15, k = 8*(lane>>4)+j) ----
  short8 whf[2][4]; short8 wxf[2]; float bv[2];
#pragma unroll
  for (int nt = 0; nt < 2; ++nt) {
    const int col = colbase + 16 * nt + lm;
    bv[nt] = bh[col];
#pragma unroll
    for (int kb = 0; kb < 4; ++kb) {
      short8 f;
#pragma unroll
      for (int j = 0; j < 8; ++j)
        f[j] = f2bf(Wh[(size_t)(32 * kb + 8 * l4 + j) * HID + col]);
      whf[nt][kb] = f;
    }
    short8 fx;
#pragma unroll
    for (int j = 0; j < 8; ++j)
      fx[j] = f2bf(Wx[(size_t)(8 * l4 + j) * HID + col]);
    wxf[nt] = fx;
  }

  const int rsel = l4 & 1;         // batch row parity this lane outputs
  const int csel = l4 >> 1;        // which 16-col tile
  const int ocol = colbase + 16 * csel + lm;

  const unsigned out_off0 =
      ((unsigned)(row0 + rsel) * T_SEQ) * (HID * 4) + (unsigned)ocol * 4;
  float* outb = out;
  float* hfinp = out + (size_t)512 * T_SEQ * HID + (size_t)(row0 + rsel) * HID + ocol;

  // LDS ptrs: h A-frag read row = lm&1 (k-offset 8*l4 folded); x A-frag read
  // row = lm&1, elems 8*l4..+7 (8 distinct 16B lines across 128 B: conflict-free)
  const short* hr0 = &hbuf[0][lm & 1][8 * l4];
  const short* hr1 = &hbuf[1][lm & 1][8 * l4];
  short* hw0 = &hbuf[0][rsel][ocol];
  short* hw1 = &hbuf[1][rsel][ocol];
  const short* xbase = &xlds[0][lm & 1][8 * l4];

  const float* xsrc = x + (size_t)row0 * T_SEQ * EMB;  // 2 contiguous rows

  const f32x4 z_  = {0.f, 0.f, 0.f, 0.f};
  const f32x4 cb0 = {bv[0], bv[0], bv[0], bv[0]};   // bias as x-MFMA C
  const f32x4 cb1 = {bv[1], bv[1], bv[1], bv[1]};

  f32x4 pA0, pA1, pB0, pB1;   // pipelined x-projection (even/odd step regs)
  float th_last = 0.f;

  // ---- stage chunk [TB, TB+TCH) of x into LDS as bf16 ----
#define STAGE(TB) do {                                                           \
    _Pragma("unroll")                                                            \
    for (int k = 0; k < (BB * TCH * EMB / 4) / 256; ++k) { /* 8 f32x4/thread */  \
      const int flat4 = tid + k * 256;                                           \
      const int e4 = flat4 & 7;                                                  \
      const int tt = (flat4 >> 3) & (TCH - 1);                                   \
      const int r  = flat4 >> 10;                                                \
      const f32x4 v4 = *(const f32x4*)(xsrc + (size_t)r * T_SEQ * EMB +          \
                                       (size_t)((TB) + tt) * EMB + e4 * 4);      \
      short4v s4;                                                                \
      s4[0] = f2bf(v4[0]); s4[1] = f2bf(v4[1]);                                  \
      s4[2] = f2bf(v4[2]); s4[3] = f2bf(v4[3]);                                  \
      *(short4v*)&xlds[tt][r][e4 * 4] = s4;                                      \
    }                                                                            \
  } while (0)

  // p(T) = x(T)@Wx + bias  (standalone, used at chunk starts)
#define PCOMP(T, P0, P1) do {                                                    \
    short8 xn = *(const short8*)(xbase + ((T) & (TCH - 1)) * (BB * EMB));        \
    P0 = MFMA(xn, wxf[0], cb0);                                                  \
    P1 = MFMA(xn, wxf[1], cb1);                                                  \
  } while (0)

  // One recurrence step. PNEXT=1: also compute p(T+1) in the dep shadow.
#define RSTEP(T, PAR, PNEXT, PIN0, PIN1, POUT0, POUT1) do {                      \
    const short* hb_ = (PAR) ? hr0 : hr1;   /* prev = PAR^1 */                   \
    short8 ah0 = *(const short8*)(hb_ + 0);                                      \
    short8 ah1 = *(const short8*)(hb_ + 32);                                     \
    short8 ah2 = *(const short8*)(hb_ + 64);                                     \
    short8 ah3 = *(const short8*)(hb_ + 96);                                     \
    f32x4 a0 = MFMA(ah0, whf[0][0], PIN0);   /* p(T) enters as C */              \
    f32x4 a1 = MFMA(ah0, whf[1][0], PIN1);                                       \
    f32x4 b0 = MFMA(ah2, whf[0][2], z_);                                         \
    f32x4 b1 = MFMA(ah2, whf[1][2], z_);                                         \
    a0 = MFMA(ah1, whf[0][1], a0);                                               \
    a1 = MFMA(ah1, whf[1][1], a1);                                               \
    b0 = MFMA(ah3, whf[0][3], b0);                                               \
    b1 = MFMA(ah3, whf[1][3], b1);                                               \
    if (PNEXT) {                             /* off-chain: p(T+1) */             \
      short8 xn = *(const short8*)(xbase + (((T) + 1) & (TCH - 1)) * (BB * EMB));\
      POUT0 = MFMA(xn, wxf[0], cb0);                                             \
      POUT1 = MFMA(xn, wxf[1], cb1);                                             \
    }                                                                            \
    float vA0 = rsel ? a0[1] : a0[0];                                            \
    float vB0 = rsel ? b0[1] : b0[0];                                            \
    float vA1 = rsel ? a1[1] : a1[0];                                            \
    float vB1 = rsel ? b1[1] : b1[0];                                            \
    float v_ = csel ? (vA1 + vB1) : (vA0 + vB0);                                 \
    float th_ = tanh_fast(v_);                                                   \
    *((PAR) ? hw1 : hw0) = f2bf(th_);   /* cur = PAR; 1 ds_write_b16 */          \
    asm volatile("global_store_dword %0, %1, %2"                                 \
                 :: "v"(out_off0 + (unsigned)(T) * 512u), "v"(th_), "s"(outb));  \
    th_last = th_;                                                               \
    asm volatile("s_waitcnt lgkmcnt(0)\n\ts_barrier" ::: "memory");              \
  } while (0)

  STAGE(0);
  __syncthreads();      // chunk 0 + hbuf init visible
  PCOMP(0, pA0, pA1);

  for (int tb = 0; tb < T_SEQ; tb += TCH) {
#pragma unroll 4
    for (int t = tb; t < tb + TCH - 2; t += 2) {
      RSTEP(t + 0, 0, 1, pA0, pA1, pB0, pB1);
      RSTEP(t + 1, 1, 1, pB0, pB1, pA0, pA1);
    }
    RSTEP(tb + TCH - 2, 0, 1, pA0, pA1, pB0, pB1);
    RSTEP(tb + TCH - 1, 1, 0, pB0, pB1, pA0, pA1);  // last of chunk: no p-next
    if (tb + TCH < T_SEQ) {
      STAGE(tb + TCH);    // xlds reads all done (previous RSTEP barrier)
      __syncthreads();
      PCOMP(tb + TCH, pA0, pA1);
    }
  }
#undef RSTEP
#undef PCOMP
#undef STAGE

  *hfinp = th_last;  // final h (t = T-1), off the loop
}

extern "C" void kernel_launch(void* const* d_in, const int* in_sizes, int n_in,
                              void* d_out, int out_size, void* d_ws, size_t ws_size,
                              hipStream_t stream) {
  const float* x  = (const float*)d_in[0];
  const float* Wx = (const float*)d_in[1];
  const float* Wh = (const float*)d_in[2];
  const float* bh = (const float*)d_in[3];
  float* out = (float*)d_out;
  (void)in_sizes; (void)n_in; (void)out_size; (void)d_ws; (void)ws_size;
  rnn_fused_kernel<<<512 / BB, 256, 0, stream>>>(x, Wx, Wh, bh, out);
}